// Round 7
// baseline (137.408 us; speedup 1.0000x reference)
//
#include <hip/hip_runtime.h>
#include <hip/hip_fp16.h>
#include <math.h>

#define BB 8
#define CC 64
#define NN 8192
#define KK 20
#define COUT 64
#define BN_EPS 1e-5

// XCD swizzle: blockIdx round-robins over 8 XCDs, so (blockIdx.x & 7) == XCD.
// Batch b pinned to XCD b keeps b's yc slice resident in that XCD's L2.

// ---------------------------------------------------------------------------
// Pass 1 (register/SGPR compute + wave-private LDS transpose for the store):
// lane = n; x column in 64 VGPRs (coalesced loads); weights wave-uniform ->
// s_load + v_fmac(v,s,v). Results go through a padded LDS tile so the global
// store writes full cache lines (round-6 direct store had 5x write amp).
// Wave wv: sub=wv>>1 picks n-half (64 n), oh=wv&1 picks o-half (32 o).
// LDS tile row = n (pad 65), cols 0..31 = p (=w1.x - w2.x), 32..63 = q (=w2.x).
// ---------------------------------------------------------------------------
__global__ __launch_bounds__(256) void pass1_yc(const float* __restrict__ x,
                                                const float* __restrict__ w,
                                                float* __restrict__ yc) {
    const int blk = blockIdx.x;          // 512 blocks
    const int b   = blk & 7;             // XCD-aligned batch
    const int ng  = blk >> 3;            // group of 128 n
    const int tid = threadIdx.x;
    const int wv   = tid >> 6;
    const int lane = tid & 63;
    const int sub = wv >> 1;             // n-subtile 0/1
    const int oh  = wv & 1;              // o-half
    const int n   = ng * 128 + sub * 64 + lane;

    __shared__ float tile[4][64][65];    // wave-private padded tiles (66.6 KB)
    float (*T)[65] = tile[wv];

    // coalesced x column load: lanes consecutive in n
    const float* xb = x + (size_t)b * CC * NN + n;
    float xr[64];
#pragma unroll
    for (int c = 0; c < 64; ++c)
        xr[c] = xb[(size_t)c * NN];

    const float* wbase = w + oh * 32 * 128;   // uniform -> s_load

    for (int o4 = 0; o4 < 8; ++o4) {
#pragma unroll
        for (int j = 0; j < 4; ++j) {
            const float* wr = wbase + (o4 * 4 + j) * 128;
            float p = 0.f, q = 0.f;
#pragma unroll
            for (int c = 0; c < 64; ++c) {
                p = fmaf(wr[c],      xr[c], p);
                q = fmaf(wr[64 + c], xr[c], q);
            }
            // bank = (lane + col) % 32 -> 2-way (free)
            T[lane][o4 * 4 + j]      = p - q;
            T[lane][32 + o4 * 4 + j] = q;
        }
    }

    // transposed, fully-coalesced store (wave-private tile: no block barrier)
    const int qq   = lane & 15;          // col quad
    const int rsub = lane >> 4;          // row within group of 4
    const int ccol = qq * 4;             // LDS col
    const int ocol = (qq < 8) ? (oh * 32 + qq * 4)
                              : (64 + oh * 32 + (qq - 8) * 4);
    float* ybase = yc + ((size_t)b * NN + ng * 128 + sub * 64) * 128;
    for (int rr = 0; rr < 16; ++rr) {
        const int r = rr * 4 + rsub;
        float4 v = {T[r][ccol], T[r][ccol + 1], T[r][ccol + 2], T[r][ccol + 3]};
        *reinterpret_cast<float4*>(ybase + (size_t)r * 128 + ocol) = v;
    }
}

// ---------------------------------------------------------------------------
// Pass 2 (float4-gather version).
// Lane layout: g = lane>>4 (k-slot), q = lane&15 (channel quad).
// hmm stored as fp16: row = [64 x max][64 x min] halves (256 B).
// ---------------------------------------------------------------------------
__global__ __launch_bounds__(256, 6) void pass2_gather(const float* __restrict__ yc,
                                                       const int* __restrict__ eidx,
                                                       __half* __restrict__ hmm,
                                                       float* __restrict__ psum,
                                                       float* __restrict__ pssq) {
    const int b  = blockIdx.x & 7;
    const int n0 = (blockIdx.x >> 3) * 32;
    const int w    = threadIdx.x >> 6;
    const int lane = threadIdx.x & 63;
    const int g = lane >> 4;   // k-slot 0..3
    const int q = lane & 15;   // channel quad

    const int* e0 = eidx + (size_t)b * NN * KK;   // edge_index[0]
    const int* e1 = e0 + (size_t)BB * NN * KK;    // edge_index[1]
    const float* yca = yc + (size_t)b * NN * 128 + 4 * q;        // wa half
    const float* ycb = yc + (size_t)b * NN * 128 + 64 + 4 * q;   // wb half

    float4 sum4 = {0.f, 0.f, 0.f, 0.f};
    float4 ssq4 = {0.f, 0.f, 0.f, 0.f};

    for (int i = 0; i < 8; ++i) {
        const int n = n0 + w * 8 + i;
        const int* r1 = e1 + (size_t)n * KK;
        const int* r0 = e0 + (size_t)n * KK;
        int i1k[5], i0k[5];
#pragma unroll
        for (int s = 0; s < 5; ++s) {
            i1k[s] = r1[4 * s + g];
            i0k[s] = r0[4 * s + g];
        }
        float4 mx = {-3.402823466e38f, -3.402823466e38f, -3.402823466e38f, -3.402823466e38f};
        float4 mn = { 3.402823466e38f,  3.402823466e38f,  3.402823466e38f,  3.402823466e38f};
#pragma unroll
        for (int s = 0; s < 5; ++s) {
            float4 v1 = *reinterpret_cast<const float4*>(yca + (size_t)i1k[s] * 128);
            float4 v0 = *reinterpret_cast<const float4*>(ycb + (size_t)i0k[s] * 128);
            float4 h;
            h.x = v1.x + v0.x; h.y = v1.y + v0.y;
            h.z = v1.z + v0.z; h.w = v1.w + v0.w;
            mx.x = fmaxf(mx.x, h.x); mx.y = fmaxf(mx.y, h.y);
            mx.z = fmaxf(mx.z, h.z); mx.w = fmaxf(mx.w, h.w);
            mn.x = fminf(mn.x, h.x); mn.y = fminf(mn.y, h.y);
            mn.z = fminf(mn.z, h.z); mn.w = fminf(mn.w, h.w);
            sum4.x += h.x; sum4.y += h.y; sum4.z += h.z; sum4.w += h.w;
            ssq4.x = fmaf(h.x, h.x, ssq4.x); ssq4.y = fmaf(h.y, h.y, ssq4.y);
            ssq4.z = fmaf(h.z, h.z, ssq4.z); ssq4.w = fmaf(h.w, h.w, ssq4.w);
        }
#pragma unroll
        for (int m = 16; m <= 32; m <<= 1) {
            mx.x = fmaxf(mx.x, __shfl_xor(mx.x, m));
            mx.y = fmaxf(mx.y, __shfl_xor(mx.y, m));
            mx.z = fmaxf(mx.z, __shfl_xor(mx.z, m));
            mx.w = fmaxf(mx.w, __shfl_xor(mx.w, m));
            mn.x = fminf(mn.x, __shfl_xor(mn.x, m));
            mn.y = fminf(mn.y, __shfl_xor(mn.y, m));
            mn.z = fminf(mn.z, __shfl_xor(mn.z, m));
            mn.w = fminf(mn.w, __shfl_xor(mn.w, m));
        }
        if (g < 2) {
            float4 v = (g == 0) ? mx : mn;
            __half2 pa = __floats2half2_rn(v.x, v.y);
            __half2 pb = __floats2half2_rn(v.z, v.w);
            uint2 pk;
            pk.x = *reinterpret_cast<unsigned*>(&pa);
            pk.y = *reinterpret_cast<unsigned*>(&pb);
            *reinterpret_cast<uint2*>(hmm + ((size_t)b * NN + n) * 128 + g * 64 + 4 * q) = pk;
        }
    }

#pragma unroll
    for (int m = 16; m <= 32; m <<= 1) {
        sum4.x += __shfl_xor(sum4.x, m); sum4.y += __shfl_xor(sum4.y, m);
        sum4.z += __shfl_xor(sum4.z, m); sum4.w += __shfl_xor(sum4.w, m);
        ssq4.x += __shfl_xor(ssq4.x, m); ssq4.y += __shfl_xor(ssq4.y, m);
        ssq4.z += __shfl_xor(ssq4.z, m); ssq4.w += __shfl_xor(ssq4.w, m);
    }
    __shared__ float rs[4][64], rq[4][64];
    if (g == 0) {
        *reinterpret_cast<float4*>(&rs[w][4 * q]) = sum4;
        *reinterpret_cast<float4*>(&rq[w][4 * q]) = ssq4;
    }
    __syncthreads();
    if (w == 0) {
        float s = rs[0][lane] + rs[1][lane] + rs[2][lane] + rs[3][lane];
        float qq = rq[0][lane] + rq[1][lane] + rq[2][lane] + rq[3][lane];
        psum[(size_t)blockIdx.x * 64 + lane] = s;
        pssq[(size_t)blockIdx.x * 64 + lane] = qq;
    }
}

// ---------------------------------------------------------------------------
// Pass 2b stage 1: 32 blocks reduce the 2048 partial rows.
// ---------------------------------------------------------------------------
__global__ __launch_bounds__(256) void pass2b_stage1(const float* __restrict__ psum,
                                                     const float* __restrict__ pssq,
                                                     double* __restrict__ p2sum,
                                                     double* __restrict__ p2ssq,
                                                     int nblocks) {
    const int t = threadIdx.x;
    const int c = t & 63, s = t >> 6;
    double sum = 0.0, ssq = 0.0;
    for (int i = blockIdx.x * 4 + s; i < nblocks; i += 32 * 4) {
        sum += (double)psum[(size_t)i * 64 + c];
        ssq += (double)pssq[(size_t)i * 64 + c];
    }
    __shared__ double ds_[4][64], dq_[4][64];
    ds_[s][c] = sum;
    dq_[s][c] = ssq;
    __syncthreads();
    if (s == 0) {
        p2sum[(size_t)blockIdx.x * 64 + c] = ds_[0][c] + ds_[1][c] + ds_[2][c] + ds_[3][c];
        p2ssq[(size_t)blockIdx.x * 64 + c] = dq_[0][c] + dq_[1][c] + dq_[2][c] + dq_[3][c];
    }
}

// ---------------------------------------------------------------------------
// Pass 2b stage 2: single block -> scale/shift.
// ---------------------------------------------------------------------------
__global__ __launch_bounds__(256) void pass2b_stage2(const double* __restrict__ p2sum,
                                                     const double* __restrict__ p2ssq,
                                                     const float* __restrict__ gamma,
                                                     const float* __restrict__ beta,
                                                     float* __restrict__ scsh) {
    const int t = threadIdx.x;
    const int c = t & 63, s = t >> 6;
    double sum = 0.0, ssq = 0.0;
    for (int i = s; i < 32; i += 4) {
        sum += p2sum[(size_t)i * 64 + c];
        ssq += p2ssq[(size_t)i * 64 + c];
    }
    __shared__ double ds_[4][64], dq_[4][64];
    ds_[s][c] = sum;
    dq_[s][c] = ssq;
    __syncthreads();
    if (s == 0) {
        double S = ds_[0][c] + ds_[1][c] + ds_[2][c] + ds_[3][c];
        double Q = dq_[0][c] + dq_[1][c] + dq_[2][c] + dq_[3][c];
        const double cnt = (double)BB * NN * KK;
        double mean = S / cnt;
        double var  = Q / cnt - mean * mean;
        float scale = (float)((double)gamma[c] / sqrt(var + BN_EPS));
        float shift = (float)((double)beta[c] - mean * (double)scale);
        scsh[c]      = scale;
        scsh[64 + c] = shift;
    }
}

// ---------------------------------------------------------------------------
// Pass 4: out[b][o][n] = relu(scale[o]*hsel + shift[o]); hmm rows are fp16.
// ---------------------------------------------------------------------------
__global__ __launch_bounds__(256) void pass4_out(const __half* __restrict__ hmm,
                                                 const float* __restrict__ scsh,
                                                 float* __restrict__ out) {
    const int b  = blockIdx.x & 7;
    const int n0 = (blockIdx.x >> 3) * 64;
    const int w    = threadIdx.x >> 6;
    const int lane = threadIdx.x & 63;

    __shared__ float ts[64][65];
    const float sc = scsh[lane];
    const float sh = scsh[64 + lane];

    for (int i = 0; i < 16; ++i) {
        const int j = w + 4 * i;
        const __half* row = hmm + ((size_t)b * NN + n0 + j) * 128;
        float hv = (sc >= 0.f) ? __half2float(row[lane])
                               : __half2float(row[64 + lane]);
        ts[j][lane] = fmaxf(0.f, fmaf(sc, hv, sh));
    }
    __syncthreads();
    for (int i = 0; i < 16; ++i) {
        const int o = w + 4 * i;
        out[((size_t)b * COUT + o) * NN + n0 + lane] = ts[lane][o];
    }
}

// ---------------------------------------------------------------------------
extern "C" void kernel_launch(void* const* d_in, const int* in_sizes, int n_in,
                              void* d_out, int out_size, void* d_ws, size_t ws_size,
                              hipStream_t stream) {
    const float* x     = (const float*)d_in[0]; // [B, C, N, 1]
    const float* wgt   = (const float*)d_in[1]; // [64, 128]
    const float* gamma = (const float*)d_in[2]; // [64]
    const float* beta  = (const float*)d_in[3]; // [64]
    const int*   eidx  = (const int*)d_in[4];   // [2, B, N, K]
    float* out = (float*)d_out;                 // [B, 64, N]

    // workspace layout
    float*  yc   = (float*)d_ws;                          // B*N*128 floats (32 MB)
    __half* hmm  = (__half*)(yc + (size_t)BB * NN * 128); // B*N*128 halves (16 MB)
    float*  psum = (float*)(hmm + (size_t)BB * NN * 128); // 2048*64 floats
    float*  pssq = psum + (size_t)(BB * (NN / 32)) * 64;  // 2048*64 floats
    float*  scsh = pssq + (size_t)(BB * (NN / 32)) * 64;  // 128 floats
    double* p2sum = (double*)(scsh + 128 + 32);           // 32*64 doubles
    double* p2ssq = p2sum + 32 * 64;                      // 32*64 doubles

    const int nblk2 = BB * (NN / 32); // 2048

    hipLaunchKernelGGL(pass1_yc, dim3(BB * (NN / 128)), dim3(256), 0, stream,
                       x, wgt, yc);
    hipLaunchKernelGGL(pass2_gather, dim3(nblk2), dim3(256), 0, stream,
                       yc, eidx, hmm, psum, pssq);
    hipLaunchKernelGGL(pass2b_stage1, dim3(32), dim3(256), 0, stream,
                       psum, pssq, p2sum, p2ssq, nblk2);
    hipLaunchKernelGGL(pass2b_stage2, dim3(1), dim3(256), 0, stream,
                       p2sum, p2ssq, gamma, beta, scsh);
    hipLaunchKernelGGL(pass4_out, dim3(BB * (NN / 64)), dim3(256), 0, stream,
                       hmm, scsh, out);
}

// Round 8
// 114.969 us; speedup vs baseline: 1.1952x; 1.1952x over previous
//
#include <hip/hip_runtime.h>
#include <hip/hip_fp16.h>
#include <math.h>

#define BB 8
#define CC 64
#define NN 8192
#define KK 20
#define COUT 64
#define BN_EPS 1e-5

// XCD swizzle: blockIdx round-robins over 8 XCDs, so (blockIdx.x & 7) == XCD.
// Batch b pinned to XCD b keeps b's yc slice resident in that XCD's L2.

// ---------------------------------------------------------------------------
// Pass 1 (register/SGPR compute + wave-private LDS transpose for the store):
// lane = n; x column in 64 VGPRs (coalesced loads); weights wave-uniform
// (wv via readfirstlane -> uniform pointer -> s_load + v_fmac(v,s,v); without
// it the round-7 build emitted 4096 vector loads/wave, VGPR 80->160).
// Store goes through a padded LDS tile so global stores write full lines
// (round-6 direct store had 5x write amp).
// ---------------------------------------------------------------------------
__global__ __launch_bounds__(256) void pass1_yc(const float* __restrict__ x,
                                                const float* __restrict__ w,
                                                float* __restrict__ yc) {
    const int blk = blockIdx.x;          // 512 blocks
    const int b   = blk & 7;             // XCD-aligned batch
    const int ng  = blk >> 3;            // group of 128 n
    const int tid = threadIdx.x;
    const int wv   = __builtin_amdgcn_readfirstlane(tid >> 6); // uniform wave id
    const int lane = tid & 63;
    const int sub = wv >> 1;             // n-subtile 0/1
    const int oh  = wv & 1;              // o-half (uniform)
    const int n   = ng * 128 + sub * 64 + lane;

    __shared__ float tile[4][64][65];    // wave-private padded tiles (66.6 KB)
    float (*T)[65] = tile[wv];

    // coalesced x column load: lanes consecutive in n
    const float* xb = x + (size_t)b * CC * NN + n;
    float xr[64];
#pragma unroll
    for (int c = 0; c < 64; ++c)
        xr[c] = xb[(size_t)c * NN];

    const float* wbase = w + oh * 32 * 128;   // uniform -> s_load

    for (int o4 = 0; o4 < 8; ++o4) {
#pragma unroll
        for (int j = 0; j < 4; ++j) {
            const float* wr = wbase + (o4 * 4 + j) * 128;
            float p = 0.f, q = 0.f;
#pragma unroll
            for (int c = 0; c < 64; ++c) {
                p = fmaf(wr[c],      xr[c], p);
                q = fmaf(wr[64 + c], xr[c], q);
            }
            // bank = (lane + col) % 32 -> 2-way (free)
            T[lane][o4 * 4 + j]      = p - q;
            T[lane][32 + o4 * 4 + j] = q;
        }
    }

    // transposed, fully-coalesced store (wave-private tile: no block barrier)
    const int qq   = lane & 15;          // col quad
    const int rsub = lane >> 4;          // row within group of 4
    const int ccol = qq * 4;             // LDS col
    const int ocol = (qq < 8) ? (oh * 32 + qq * 4)
                              : (64 + oh * 32 + (qq - 8) * 4);
    float* ybase = yc + ((size_t)b * NN + ng * 128 + sub * 64) * 128;
    for (int rr = 0; rr < 16; ++rr) {
        const int r = rr * 4 + rsub;
        float4 v = {T[r][ccol], T[r][ccol + 1], T[r][ccol + 2], T[r][ccol + 3]};
        *reinterpret_cast<float4*>(ybase + (size_t)r * 128 + ocol) = v;
    }
}

// ---------------------------------------------------------------------------
// Pass 2 (float4-gather version).
// Lane layout: g = lane>>4 (k-slot), q = lane&15 (channel quad).
// hmm stored as fp16: row = [64 x max][64 x min] halves (256 B).
// ---------------------------------------------------------------------------
__global__ __launch_bounds__(256, 6) void pass2_gather(const float* __restrict__ yc,
                                                       const int* __restrict__ eidx,
                                                       __half* __restrict__ hmm,
                                                       float* __restrict__ psum,
                                                       float* __restrict__ pssq) {
    const int b  = blockIdx.x & 7;
    const int n0 = (blockIdx.x >> 3) * 32;
    const int w    = threadIdx.x >> 6;
    const int lane = threadIdx.x & 63;
    const int g = lane >> 4;   // k-slot 0..3
    const int q = lane & 15;   // channel quad

    const int* e0 = eidx + (size_t)b * NN * KK;   // edge_index[0]
    const int* e1 = e0 + (size_t)BB * NN * KK;    // edge_index[1]
    const float* yca = yc + (size_t)b * NN * 128 + 4 * q;        // wa half
    const float* ycb = yc + (size_t)b * NN * 128 + 64 + 4 * q;   // wb half

    float4 sum4 = {0.f, 0.f, 0.f, 0.f};
    float4 ssq4 = {0.f, 0.f, 0.f, 0.f};

    for (int i = 0; i < 8; ++i) {
        const int n = n0 + w * 8 + i;
        const int* r1 = e1 + (size_t)n * KK;
        const int* r0 = e0 + (size_t)n * KK;
        int i1k[5], i0k[5];
#pragma unroll
        for (int s = 0; s < 5; ++s) {
            i1k[s] = r1[4 * s + g];
            i0k[s] = r0[4 * s + g];
        }
        float4 mx = {-3.402823466e38f, -3.402823466e38f, -3.402823466e38f, -3.402823466e38f};
        float4 mn = { 3.402823466e38f,  3.402823466e38f,  3.402823466e38f,  3.402823466e38f};
#pragma unroll
        for (int s = 0; s < 5; ++s) {
            float4 v1 = *reinterpret_cast<const float4*>(yca + (size_t)i1k[s] * 128);
            float4 v0 = *reinterpret_cast<const float4*>(ycb + (size_t)i0k[s] * 128);
            float4 h;
            h.x = v1.x + v0.x; h.y = v1.y + v0.y;
            h.z = v1.z + v0.z; h.w = v1.w + v0.w;
            mx.x = fmaxf(mx.x, h.x); mx.y = fmaxf(mx.y, h.y);
            mx.z = fmaxf(mx.z, h.z); mx.w = fmaxf(mx.w, h.w);
            mn.x = fminf(mn.x, h.x); mn.y = fminf(mn.y, h.y);
            mn.z = fminf(mn.z, h.z); mn.w = fminf(mn.w, h.w);
            sum4.x += h.x; sum4.y += h.y; sum4.z += h.z; sum4.w += h.w;
            ssq4.x = fmaf(h.x, h.x, ssq4.x); ssq4.y = fmaf(h.y, h.y, ssq4.y);
            ssq4.z = fmaf(h.z, h.z, ssq4.z); ssq4.w = fmaf(h.w, h.w, ssq4.w);
        }
#pragma unroll
        for (int m = 16; m <= 32; m <<= 1) {
            mx.x = fmaxf(mx.x, __shfl_xor(mx.x, m));
            mx.y = fmaxf(mx.y, __shfl_xor(mx.y, m));
            mx.z = fmaxf(mx.z, __shfl_xor(mx.z, m));
            mx.w = fmaxf(mx.w, __shfl_xor(mx.w, m));
            mn.x = fminf(mn.x, __shfl_xor(mn.x, m));
            mn.y = fminf(mn.y, __shfl_xor(mn.y, m));
            mn.z = fminf(mn.z, __shfl_xor(mn.z, m));
            mn.w = fminf(mn.w, __shfl_xor(mn.w, m));
        }
        if (g < 2) {
            float4 v = (g == 0) ? mx : mn;
            __half2 pa = __floats2half2_rn(v.x, v.y);
            __half2 pb = __floats2half2_rn(v.z, v.w);
            uint2 pk;
            pk.x = *reinterpret_cast<unsigned*>(&pa);
            pk.y = *reinterpret_cast<unsigned*>(&pb);
            *reinterpret_cast<uint2*>(hmm + ((size_t)b * NN + n) * 128 + g * 64 + 4 * q) = pk;
        }
    }

#pragma unroll
    for (int m = 16; m <= 32; m <<= 1) {
        sum4.x += __shfl_xor(sum4.x, m); sum4.y += __shfl_xor(sum4.y, m);
        sum4.z += __shfl_xor(sum4.z, m); sum4.w += __shfl_xor(sum4.w, m);
        ssq4.x += __shfl_xor(ssq4.x, m); ssq4.y += __shfl_xor(ssq4.y, m);
        ssq4.z += __shfl_xor(ssq4.z, m); ssq4.w += __shfl_xor(ssq4.w, m);
    }
    __shared__ float rs[4][64], rq[4][64];
    if (g == 0) {
        *reinterpret_cast<float4*>(&rs[w][4 * q]) = sum4;
        *reinterpret_cast<float4*>(&rq[w][4 * q]) = ssq4;
    }
    __syncthreads();
    if (w == 0) {
        float s = rs[0][lane] + rs[1][lane] + rs[2][lane] + rs[3][lane];
        float qq = rq[0][lane] + rq[1][lane] + rq[2][lane] + rq[3][lane];
        psum[(size_t)blockIdx.x * 64 + lane] = s;
        pssq[(size_t)blockIdx.x * 64 + lane] = qq;
    }
}

// ---------------------------------------------------------------------------
// Pass 2b stage 1: 32 blocks reduce the 2048 partial rows.
// ---------------------------------------------------------------------------
__global__ __launch_bounds__(256) void pass2b_stage1(const float* __restrict__ psum,
                                                     const float* __restrict__ pssq,
                                                     double* __restrict__ p2sum,
                                                     double* __restrict__ p2ssq,
                                                     int nblocks) {
    const int t = threadIdx.x;
    const int c = t & 63, s = t >> 6;
    double sum = 0.0, ssq = 0.0;
    for (int i = blockIdx.x * 4 + s; i < nblocks; i += 32 * 4) {
        sum += (double)psum[(size_t)i * 64 + c];
        ssq += (double)pssq[(size_t)i * 64 + c];
    }
    __shared__ double ds_[4][64], dq_[4][64];
    ds_[s][c] = sum;
    dq_[s][c] = ssq;
    __syncthreads();
    if (s == 0) {
        p2sum[(size_t)blockIdx.x * 64 + c] = ds_[0][c] + ds_[1][c] + ds_[2][c] + ds_[3][c];
        p2ssq[(size_t)blockIdx.x * 64 + c] = dq_[0][c] + dq_[1][c] + dq_[2][c] + dq_[3][c];
    }
}

// ---------------------------------------------------------------------------
// Pass 2b stage 2: single block -> scale/shift.
// ---------------------------------------------------------------------------
__global__ __launch_bounds__(256) void pass2b_stage2(const double* __restrict__ p2sum,
                                                     const double* __restrict__ p2ssq,
                                                     const float* __restrict__ gamma,
                                                     const float* __restrict__ beta,
                                                     float* __restrict__ scsh) {
    const int t = threadIdx.x;
    const int c = t & 63, s = t >> 6;
    double sum = 0.0, ssq = 0.0;
    for (int i = s; i < 32; i += 4) {
        sum += p2sum[(size_t)i * 64 + c];
        ssq += p2ssq[(size_t)i * 64 + c];
    }
    __shared__ double ds_[4][64], dq_[4][64];
    ds_[s][c] = sum;
    dq_[s][c] = ssq;
    __syncthreads();
    if (s == 0) {
        double S = ds_[0][c] + ds_[1][c] + ds_[2][c] + ds_[3][c];
        double Q = dq_[0][c] + dq_[1][c] + dq_[2][c] + dq_[3][c];
        const double cnt = (double)BB * NN * KK;
        double mean = S / cnt;
        double var  = Q / cnt - mean * mean;
        float scale = (float)((double)gamma[c] / sqrt(var + BN_EPS));
        float shift = (float)((double)beta[c] - mean * (double)scale);
        scsh[c]      = scale;
        scsh[64 + c] = shift;
    }
}

// ---------------------------------------------------------------------------
// Pass 4: out[b][o][n] = relu(scale[o]*hsel + shift[o]); hmm rows are fp16.
// ---------------------------------------------------------------------------
__global__ __launch_bounds__(256) void pass4_out(const __half* __restrict__ hmm,
                                                 const float* __restrict__ scsh,
                                                 float* __restrict__ out) {
    const int b  = blockIdx.x & 7;
    const int n0 = (blockIdx.x >> 3) * 64;
    const int w    = threadIdx.x >> 6;
    const int lane = threadIdx.x & 63;

    __shared__ float ts[64][65];
    const float sc = scsh[lane];
    const float sh = scsh[64 + lane];

    for (int i = 0; i < 16; ++i) {
        const int j = w + 4 * i;
        const __half* row = hmm + ((size_t)b * NN + n0 + j) * 128;
        float hv = (sc >= 0.f) ? __half2float(row[lane])
                               : __half2float(row[64 + lane]);
        ts[j][lane] = fmaxf(0.f, fmaf(sc, hv, sh));
    }
    __syncthreads();
    for (int i = 0; i < 16; ++i) {
        const int o = w + 4 * i;
        out[((size_t)b * COUT + o) * NN + n0 + lane] = ts[lane][o];
    }
}

// ---------------------------------------------------------------------------
extern "C" void kernel_launch(void* const* d_in, const int* in_sizes, int n_in,
                              void* d_out, int out_size, void* d_ws, size_t ws_size,
                              hipStream_t stream) {
    const float* x     = (const float*)d_in[0]; // [B, C, N, 1]
    const float* wgt   = (const float*)d_in[1]; // [64, 128]
    const float* gamma = (const float*)d_in[2]; // [64]
    const float* beta  = (const float*)d_in[3]; // [64]
    const int*   eidx  = (const int*)d_in[4];   // [2, B, N, K]
    float* out = (float*)d_out;                 // [B, 64, N]

    // workspace layout
    float*  yc   = (float*)d_ws;                          // B*N*128 floats (32 MB)
    __half* hmm  = (__half*)(yc + (size_t)BB * NN * 128); // B*N*128 halves (16 MB)
    float*  psum = (float*)(hmm + (size_t)BB * NN * 128); // 2048*64 floats
    float*  pssq = psum + (size_t)(BB * (NN / 32)) * 64;  // 2048*64 floats
    float*  scsh = pssq + (size_t)(BB * (NN / 32)) * 64;  // 128 floats
    double* p2sum = (double*)(scsh + 128 + 32);           // 32*64 doubles
    double* p2ssq = p2sum + 32 * 64;                      // 32*64 doubles

    const int nblk2 = BB * (NN / 32); // 2048

    hipLaunchKernelGGL(pass1_yc, dim3(BB * (NN / 128)), dim3(256), 0, stream,
                       x, wgt, yc);
    hipLaunchKernelGGL(pass2_gather, dim3(nblk2), dim3(256), 0, stream,
                       yc, eidx, hmm, psum, pssq);
    hipLaunchKernelGGL(pass2b_stage1, dim3(32), dim3(256), 0, stream,
                       psum, pssq, p2sum, p2ssq, nblk2);
    hipLaunchKernelGGL(pass2b_stage2, dim3(1), dim3(256), 0, stream,
                       p2sum, p2ssq, gamma, beta, scsh);
    hipLaunchKernelGGL(pass4_out, dim3(BB * (NN / 64)), dim3(256), 0, stream,
                       hmm, scsh, out);
}